// Round 4
// baseline (157.080 us; speedup 1.0000x reference)
//
#include <hip/hip_runtime.h>

#define B_    4
#define C_    256
#define Kk    7
#define GC_   16
#define G_    16
#define RED_  64
#define H_    56
#define W_    56
#define HW_   3136
#define KK_   49
#define KG_   784
#define HP_   62
#define WP_   64
#define NP_   12544
#define NQ_   784

typedef float  f4    __attribute__((ext_vector_type(4)));
typedef float  f32x4 __attribute__((ext_vector_type(4)));
typedef __bf16 bf16x8 __attribute__((ext_vector_type(8)));
typedef __bf16 bf16x4 __attribute__((ext_vector_type(4)));
typedef unsigned short u16;
typedef u16    u16x4 __attribute__((ext_vector_type(4)));

__device__ __forceinline__ f4 ld4(const float* p) { return *(const f4*)p; }
__device__ __forceinline__ void st4(float* p, f4 v) { *(f4*)p = v; }
__device__ __forceinline__ float bf2f(u16 u) {
    return __uint_as_float(((unsigned)u) << 16);
}
__device__ __forceinline__ bf16x8 pack8(f4 lo, f4 hi) {
    bf16x8 r;
    r[0] = (__bf16)lo[0]; r[1] = (__bf16)lo[1]; r[2] = (__bf16)lo[2]; r[3] = (__bf16)lo[3];
    r[4] = (__bf16)hi[0]; r[5] = (__bf16)hi[1]; r[6] = (__bf16)hi[2]; r[7] = (__bf16)hi[3];
    return r;
}

// ---------------------------------------------------------------------------
// Pad x -> xp[b][c][62][64] f32, zero halo of 3. 4 elems/thread, f4 stores.
__global__ __launch_bounds__(256) void pad_kernel(const float* __restrict__ x,
                                                  float* __restrict__ xp) {
    const int idx4 = blockIdx.x * 256 + threadIdx.x;   // quad index
    const int wq   = idx4 & 15;                        // 16 quads per 64-col row
    const int rest = idx4 >> 4;
    const int hp   = rest % HP_;
    const int bc   = rest / HP_;
    const int h    = hp - 3;
    const int w0   = wq * 4 - 3;
    f4 v = {0.f, 0.f, 0.f, 0.f};
    if (h >= 0 && h < H_) {
        const float* xr = x + (size_t)bc * HW_ + h * W_;
        if (w0 >= 0 && w0 + 3 < W_) {
            v = ld4(xr + w0);                          // dword-aligned unaligned-16B ok
        } else {
#pragma unroll
            for (int j = 0; j < 4; ++j) {
                const int w = w0 + j;
                if (w >= 0 && w < W_) v[j] = xr[w];
            }
        }
    }
    st4(xp + (size_t)idx4 * 4, v);
}

// ---------------------------------------------------------------------------
// gen1: t[px][64] bf16 = relu(w1 @ x + b1). thread = 1 px x 4 o.
// grid (49, 16), block 256 -> 3136 waves. x loads 4B coalesced, w1 -> s_load.
__global__ __launch_bounds__(256) void gen1_kernel(const float* __restrict__ x,
                                                   const float* __restrict__ w1,
                                                   const float* __restrict__ b1,
                                                   __bf16* __restrict__ t) {
    const int px = blockIdx.x * 256 + threadIdx.x;     // 0..12543
    const int o0 = blockIdx.y * 4;                     // SGPR-uniform
    const int b  = px / HW_;
    const int p  = px - b * HW_;
    const float* xb = x + (size_t)b * C_ * HW_ + p;
    const float* wr = w1 + (size_t)o0 * C_;
    float a0 = 0.f, a1 = 0.f, a2 = 0.f, a3 = 0.f;
#pragma unroll 16
    for (int c = 0; c < C_; ++c) {
        const float xv = xb[(size_t)c * HW_];
        a0 = fmaf(wr[c],          xv, a0);
        a1 = fmaf(wr[c + C_],     xv, a1);
        a2 = fmaf(wr[c + 2 * C_], xv, a2);
        a3 = fmaf(wr[c + 3 * C_], xv, a3);
    }
    bf16x4 pk;
    pk[0] = (__bf16)fmaxf(a0 + b1[o0 + 0], 0.f);
    pk[1] = (__bf16)fmaxf(a1 + b1[o0 + 1], 0.f);
    pk[2] = (__bf16)fmaxf(a2 + b1[o0 + 2], 0.f);
    pk[3] = (__bf16)fmaxf(a3 + b1[o0 + 3], 0.f);
    *(bf16x4*)(t + (size_t)px * RED_ + o0) = pk;
}

// ---------------------------------------------------------------------------
// gen2 (MFMA): wgt[b][784][3136] bf16 = w2 @ t + b2.
// grid (49 px-chunks of 256, 13 m-chunks of 64), block 256 = 4 waves x 64 px.
// B-fragments (t) loaded once per wave, reused across all m-tiles.
__global__ __launch_bounds__(256) void gen2_mfma(const __bf16* __restrict__ t,
                                                 const float* __restrict__ w2,
                                                 const float* __restrict__ b2,
                                                 __bf16* __restrict__ wgt) {
    const int lane = threadIdx.x & 63;
    const int wave = threadIdx.x >> 6;
    const int row  = lane & 15;
    const int kg   = lane >> 4;
    const int P0   = blockIdx.x * 256 + wave * 64;
    const int k0   = blockIdx.y * 64;
    const int nMt  = (blockIdx.y == 12) ? 1 : 4;       // 784 = 12*64 + 16

    bf16x8 bfrag[4][2];
#pragma unroll
    for (int cg = 0; cg < 4; ++cg)
#pragma unroll
        for (int ks = 0; ks < 2; ++ks)
            bfrag[cg][ks] = *(const bf16x8*)(t + (size_t)(P0 + cg * 16 + row) * RED_
                                               + ks * 32 + kg * 8);

    for (int mt = 0; mt < nMt; ++mt) {
        const int kr = k0 + mt * 16 + row;
        const float* w2r = w2 + (size_t)kr * RED_ + kg * 8;
        const bf16x8 afr0 = pack8(ld4(w2r),      ld4(w2r + 4));
        const bf16x8 afr1 = pack8(ld4(w2r + 32), ld4(w2r + 36));
        f32x4 acc[4] = {f32x4(0.f), f32x4(0.f), f32x4(0.f), f32x4(0.f)};
#pragma unroll
        for (int cg = 0; cg < 4; ++cg) {
            acc[cg] = __builtin_amdgcn_mfma_f32_16x16x32_bf16(afr0, bfrag[cg][0], acc[cg], 0, 0, 0);
            acc[cg] = __builtin_amdgcn_mfma_f32_16x16x32_bf16(afr1, bfrag[cg][1], acc[cg], 0, 0, 0);
        }
        const f4 bias = ld4(b2 + k0 + mt * 16 + kg * 4);
#pragma unroll
        for (int cg = 0; cg < 4; ++cg) {
            const int Pcg = P0 + cg * 16;              // 16 | 3136: never crosses b
            const int b   = Pcg / HW_;
            const int p   = Pcg - b * HW_ + row;
            const size_t base = ((size_t)b * KG_ + (size_t)(k0 + mt * 16 + kg * 4)) * HW_ + p;
#pragma unroll
            for (int j = 0; j < 4; ++j)
                wgt[base + (size_t)j * HW_] = (__bf16)(acc[cg][j] + bias[j]);
        }
    }
}

// ---------------------------------------------------------------------------
// inv: software-pipelined over kh. thread = 4 px x 2 ch.
// grid (13, 16 g, 8 = b*2 + chhalf), block 256 -> 6656 waves.
#define WIN(arr, i) (arr[(i) >> 2][(i) & 3])
__global__ __launch_bounds__(256) void inv_kernel(const float* __restrict__ xp,
                                                  const u16* __restrict__ wgt,
                                                  float* __restrict__ out) {
    const int tid  = threadIdx.x;
    const int wave = tid >> 6;
    const int qi   = (tid & 63) >> 2;
    const int cs   = tid & 3;
    const int q    = blockIdx.x * 64 + wave * 16 + qi;
    if (q >= NQ_) return;
    const int g    = blockIdx.y;
    const int z    = blockIdx.z;
    const int b    = z >> 1;
    const int c0   = (z & 1) * 8 + cs * 2;
    const int p0   = q * 4;
    const int rowp = q / 14;
    const int w0   = (q % 14) * 4;

    const u16* wb = wgt + ((size_t)b * KG_ + (size_t)g * KK_) * HW_ + p0;
    const float* x0 = xp + (size_t)(b * C_ + g * GC_ + c0) * HP_ * WP_
                         + (size_t)rowp * WP_ + w0;
    const float* x1 = x0 + (size_t)HP_ * WP_;

    u16x4 tA[7]; f4 a0[3], a1[3];
#pragma unroll
    for (int kw = 0; kw < 7; ++kw) tA[kw] = *(const u16x4*)(wb + (size_t)kw * HW_);
#pragma unroll
    for (int j = 0; j < 3; ++j) { a0[j] = ld4(x0 + j * 4); a1[j] = ld4(x1 + j * 4); }

    f4 acc0 = {0.f, 0.f, 0.f, 0.f}, acc1 = {0.f, 0.f, 0.f, 0.f};

#pragma unroll
    for (int kh = 0; kh < 7; ++kh) {
        u16x4 tB[7]; f4 b0[3], b1v[3];
        if (kh < 6) {                                   // prefetch next row
            const u16* wn = wb + (size_t)((kh + 1) * 7) * HW_;
#pragma unroll
            for (int kw = 0; kw < 7; ++kw)
                tB[kw] = *(const u16x4*)(wn + (size_t)kw * HW_);
            const float* xr0 = x0 + (size_t)(kh + 1) * WP_;
            const float* xr1 = x1 + (size_t)(kh + 1) * WP_;
#pragma unroll
            for (int j = 0; j < 3; ++j) { b0[j] = ld4(xr0 + j * 4); b1v[j] = ld4(xr1 + j * 4); }
        }
        float tf[7][4];
#pragma unroll
        for (int kw = 0; kw < 7; ++kw)
#pragma unroll
            for (int j = 0; j < 4; ++j) tf[kw][j] = bf2f(tA[kw][j]);
#pragma unroll
        for (int kw = 0; kw < 7; ++kw)
#pragma unroll
            for (int j = 0; j < 4; ++j) {
                acc0[j] = fmaf(tf[kw][j], WIN(a0, j + kw), acc0[j]);
                acc1[j] = fmaf(tf[kw][j], WIN(a1, j + kw), acc1[j]);
            }
        if (kh < 6) {
#pragma unroll
            for (int kw = 0; kw < 7; ++kw) tA[kw] = tB[kw];
#pragma unroll
            for (int j = 0; j < 3; ++j) { a0[j] = b0[j]; a1[j] = b1v[j]; }
        }
    }

    float* ob = out + (size_t)(b * C_ + g * GC_ + c0) * HW_ + p0;
    st4(ob, acc0);
    st4(ob + HW_, acc1);
}

// ---------------------------------------------------------------------------
extern "C" void kernel_launch(void* const* d_in, const int* in_sizes, int n_in,
                              void* d_out, int out_size, void* d_ws, size_t ws_size,
                              hipStream_t stream) {
    const float* x  = (const float*)d_in[0];
    const float* w1 = (const float*)d_in[1];
    const float* b1 = (const float*)d_in[2];
    const float* w2 = (const float*)d_in[3];
    const float* b2 = (const float*)d_in[4];
    float* out = (float*)d_out;

    // ws: xp f32 (16.25 MB) | t bf16 (1.6 MB) | wgt bf16 (19.7 MB)
    char* ws = (char*)d_ws;
    float*  xp  = (float*)ws;
    __bf16* t   = (__bf16*)(ws + (size_t)B_ * C_ * HP_ * WP_ * 4);
    __bf16* wgt = (__bf16*)(ws + (size_t)B_ * C_ * HP_ * WP_ * 4 + (size_t)NP_ * RED_ * 2);

    pad_kernel <<<dim3((B_ * C_ * HP_ * WP_) / 1024), 256, 0, stream>>>(x, xp);
    gen1_kernel<<<dim3(49, 16),     256, 0, stream>>>(x, w1, b1, t);
    gen2_mfma  <<<dim3(49, 13),     256, 0, stream>>>(t, w2, b2, wgt);
    inv_kernel <<<dim3(13, G_, 8),  256, 0, stream>>>(xp, (const u16*)wgt, out);
}

// Round 5
// 133.827 us; speedup vs baseline: 1.1738x; 1.1738x over previous
//
#include <hip/hip_runtime.h>

#define B_    4
#define C_    256
#define Kk    7
#define GC_   16
#define G_    16
#define RED_  64
#define H_    56
#define W_    56
#define HW_   3136
#define KK_   49
#define KG_   784
#define NP_   12544

typedef float  f4    __attribute__((ext_vector_type(4)));
typedef float  f32x4 __attribute__((ext_vector_type(4)));
typedef __bf16 bf16x8 __attribute__((ext_vector_type(8)));
typedef __bf16 bf16x4 __attribute__((ext_vector_type(4)));
typedef unsigned short u16;
typedef u16    u16x4 __attribute__((ext_vector_type(4)));

__device__ __forceinline__ f4 ld4(const float* p) { return *(const f4*)p; }
__device__ __forceinline__ void st4(float* p, f4 v) { *(f4*)p = v; }
__device__ __forceinline__ float bf2f(u16 u) {
    return __uint_as_float(((unsigned)u) << 16);
}
__device__ __forceinline__ bf16x8 pack8(f4 lo, f4 hi) {
    bf16x8 r;
    r[0] = (__bf16)lo[0]; r[1] = (__bf16)lo[1]; r[2] = (__bf16)lo[2]; r[3] = (__bf16)lo[3];
    r[4] = (__bf16)hi[0]; r[5] = (__bf16)hi[1]; r[6] = (__bf16)hi[2]; r[7] = (__bf16)hi[3];
    return r;
}

// ---------------------------------------------------------------------------
// xt: transpose x f32 [b][c][p] -> xt bf16 [P][256] (c contiguous).
// Tile 64 P x 64 c via LDS. grid (196, 4), block 256.
__global__ __launch_bounds__(256) void xt_kernel(const float* __restrict__ x,
                                                 __bf16* __restrict__ xt) {
    __shared__ __bf16 lt[64][68];          // [p][c], stride 68 u16
    const int tid = threadIdx.x;
    const int P0  = blockIdx.x * 64;
    const int c0  = blockIdx.y * 64;
    const int b   = P0 / HW_;              // 64 | 3136: never crosses b
    const int p0  = P0 - b * HW_;

    const int pq  = tid & 15;              // p-quad 0..15
    const int crb = tid >> 4;
#pragma unroll
    for (int i = 0; i < 4; ++i) {
        const int cr = crb + i * 16;
        const f4 v = ld4(x + (size_t)(b * C_ + c0 + cr) * HW_ + p0 + pq * 4);
#pragma unroll
        for (int j = 0; j < 4; ++j) lt[pq * 4 + j][cr] = (__bf16)v[j];
    }
    __syncthreads();
    const int cq  = tid & 15;              // c-quad 0..15
    const int plb = tid >> 4;
#pragma unroll
    for (int i = 0; i < 4; ++i) {
        const int pl = plb + i * 16;
        const bf16x4 rv = *(const bf16x4*)&lt[pl][cq * 4];
        *(bf16x4*)(xt + (size_t)(P0 + pl) * C_ + c0 + cq * 4) = rv;
    }
}

// ---------------------------------------------------------------------------
// gen1 (MFMA): t[P][64] bf16 = relu(w1 @ x + b1).  A = w1 (64x256), B = xt.
// grid (49), block 256 = 4 waves x 64 px. 128 MFMA/wave.
__global__ __launch_bounds__(256) void gen1m(const __bf16* __restrict__ xt,
                                             const float* __restrict__ w1,
                                             const float* __restrict__ b1,
                                             __bf16* __restrict__ t) {
    const int lane = threadIdx.x & 63;
    const int wave = threadIdx.x >> 6;
    const int row  = lane & 15;
    const int kg   = lane >> 4;
    const int P0   = blockIdx.x * 256 + wave * 64;

    f32x4 acc[4][4];                       // [mt][cg]
#pragma unroll
    for (int m = 0; m < 4; ++m)
#pragma unroll
        for (int c = 0; c < 4; ++c) acc[m][c] = f32x4(0.f);

#pragma unroll
    for (int ks = 0; ks < 8; ++ks) {
        bf16x8 af[4], bf[4];
#pragma unroll
        for (int mt = 0; mt < 4; ++mt) {
            const float* wr = w1 + (size_t)(mt * 16 + row) * C_ + ks * 32 + kg * 8;
            af[mt] = pack8(ld4(wr), ld4(wr + 4));
        }
#pragma unroll
        for (int cg = 0; cg < 4; ++cg)
            bf[cg] = *(const bf16x8*)(xt + (size_t)(P0 + cg * 16 + row) * C_
                                         + ks * 32 + kg * 8);
#pragma unroll
        for (int mt = 0; mt < 4; ++mt)
#pragma unroll
            for (int cg = 0; cg < 4; ++cg)
                acc[mt][cg] = __builtin_amdgcn_mfma_f32_16x16x32_bf16(
                    af[mt], bf[cg], acc[mt][cg], 0, 0, 0);
    }

#pragma unroll
    for (int mt = 0; mt < 4; ++mt) {
        const f4 bias = ld4(b1 + mt * 16 + kg * 4);
#pragma unroll
        for (int cg = 0; cg < 4; ++cg) {
            bf16x4 pk;
#pragma unroll
            for (int j = 0; j < 4; ++j)
                pk[j] = (__bf16)fmaxf(acc[mt][cg][j] + bias[j], 0.f);
            *(bf16x4*)(t + (size_t)(P0 + cg * 16 + row) * RED_ + mt * 16 + kg * 4) = pk;
        }
    }
}

// ---------------------------------------------------------------------------
// gen2 (MFMA): wgt[b][784][3136] bf16 = w2 @ t + b2.  (unchanged from r4)
__global__ __launch_bounds__(256) void gen2_mfma(const __bf16* __restrict__ t,
                                                 const float* __restrict__ w2,
                                                 const float* __restrict__ b2,
                                                 __bf16* __restrict__ wgt) {
    const int lane = threadIdx.x & 63;
    const int wave = threadIdx.x >> 6;
    const int row  = lane & 15;
    const int kg   = lane >> 4;
    const int P0   = blockIdx.x * 256 + wave * 64;
    const int k0   = blockIdx.y * 64;
    const int nMt  = (blockIdx.y == 12) ? 1 : 4;       // 784 = 12*64 + 16

    bf16x8 bfrag[4][2];
#pragma unroll
    for (int cg = 0; cg < 4; ++cg)
#pragma unroll
        for (int ks = 0; ks < 2; ++ks)
            bfrag[cg][ks] = *(const bf16x8*)(t + (size_t)(P0 + cg * 16 + row) * RED_
                                               + ks * 32 + kg * 8);

    for (int mt = 0; mt < nMt; ++mt) {
        const int kr = k0 + mt * 16 + row;
        const float* w2r = w2 + (size_t)kr * RED_ + kg * 8;
        const bf16x8 afr0 = pack8(ld4(w2r),      ld4(w2r + 4));
        const bf16x8 afr1 = pack8(ld4(w2r + 32), ld4(w2r + 36));
        f32x4 acc[4] = {f32x4(0.f), f32x4(0.f), f32x4(0.f), f32x4(0.f)};
#pragma unroll
        for (int cg = 0; cg < 4; ++cg) {
            acc[cg] = __builtin_amdgcn_mfma_f32_16x16x32_bf16(afr0, bfrag[cg][0], acc[cg], 0, 0, 0);
            acc[cg] = __builtin_amdgcn_mfma_f32_16x16x32_bf16(afr1, bfrag[cg][1], acc[cg], 0, 0, 0);
        }
        const f4 bias = ld4(b2 + k0 + mt * 16 + kg * 4);
#pragma unroll
        for (int cg = 0; cg < 4; ++cg) {
            const int Pcg = P0 + cg * 16;
            const int b   = Pcg / HW_;
            const int p   = Pcg - b * HW_ + row;
            const size_t base = ((size_t)b * KG_ + (size_t)(k0 + mt * 16 + kg * 4)) * HW_ + p;
#pragma unroll
            for (int j = 0; j < 4; ++j)
                wgt[base + (size_t)j * HW_] = (__bf16)(acc[cg][j] + bias[j]);
        }
    }
}

// ---------------------------------------------------------------------------
// inv (LDS-staged): block = (b, g, band of 4 output rows).
// xs: x f32 [16][10][68] staged w/ halo+zero-pad; wsm: taps bf16 [49][4][56].
// grid (14, 16, 4), block 256.
#define BR_  4
#define XR_  10
#define XST_ 68
__global__ __launch_bounds__(256) void inv_kernel(const float* __restrict__ x,
                                                  const u16* __restrict__ wgt,
                                                  float* __restrict__ out) {
    __shared__ float xs[GC_][XR_][XST_];   // 43520 B
    __shared__ u16   wsm[KK_][BR_][W_];    // 21952 B  (total 65472 <= 64 KiB)
    const int tid = threadIdx.x;
    const int r0  = blockIdx.x * BR_;
    const int g   = blockIdx.y;
    const int b   = blockIdx.z;

    // stage xs: 16 ch x 10 rows x 16 col-quads = 2560 quads
    for (int idx = tid; idx < GC_ * XR_ * 16; idx += 256) {
        const int c   = idx / (XR_ * 16);
        const int rem = idx - c * (XR_ * 16);
        const int hr  = rem >> 4;
        const int wq  = rem & 15;
        const int h   = r0 - 3 + hr;
        f4 v = {0.f, 0.f, 0.f, 0.f};
        if (h >= 0 && h < H_) {
            const float* xr_ = x + (size_t)(b * C_ + g * GC_ + c) * HW_ + h * W_;
            const int w0 = wq * 4 - 3;
            if (wq >= 1 && wq <= 13) {
                v = ld4(xr_ + w0);
            } else {
#pragma unroll
                for (int j = 0; j < 4; ++j) {
                    const int w = w0 + j;
                    if (w >= 0 && w < W_) v[j] = xr_[w];
                }
            }
        }
        *(f4*)&xs[c][hr][wq * 4] = v;
    }
    // stage taps: 49 k x 4 rows x 14 col-quads = 2744 quads
    for (int idx = tid; idx < KK_ * BR_ * 14; idx += 256) {
        const int k   = idx / (BR_ * 14);
        const int rem = idx - k * (BR_ * 14);
        const int r   = rem / 14;
        const int cq  = rem - r * 14;
        const u16x4 v = *(const u16x4*)(wgt + ((size_t)b * KG_ + (size_t)g * KK_ + k) * HW_
                                            + (r0 + r) * W_ + cq * 4);
        *(u16x4*)&wsm[k][r][cq * 4] = v;
    }
    __syncthreads();

    if (tid >= 224) return;
    const int cq  = tid % 14;
    const int r   = (tid / 14) & 3;
    const int cg4 = tid / 56;              // channel group of 4

    f4 acc[4] = {f4(0.f), f4(0.f), f4(0.f), f4(0.f)};
#pragma unroll
    for (int kh = 0; kh < Kk; ++kh) {
        float tf[7][4];
#pragma unroll
        for (int kw = 0; kw < 7; ++kw) {
            const u16x4 tv = *(const u16x4*)&wsm[kh * 7 + kw][r][cq * 4];
#pragma unroll
            for (int j = 0; j < 4; ++j) tf[kw][j] = bf2f(tv[j]);
        }
        const int hr = r + kh;
#pragma unroll
        for (int ci = 0; ci < 4; ++ci) {
            const float* xrow = &xs[cg4 * 4 + ci][hr][cq * 4];
            const f4 x0 = ld4(xrow), x1 = ld4(xrow + 4), x2 = ld4(xrow + 8);
            float xw[12];
#pragma unroll
            for (int j = 0; j < 4; ++j) { xw[j] = x0[j]; xw[4 + j] = x1[j]; xw[8 + j] = x2[j]; }
#pragma unroll
            for (int kw = 0; kw < 7; ++kw)
#pragma unroll
                for (int j = 0; j < 4; ++j)
                    acc[ci][j] = fmaf(tf[kw][j], xw[j + kw], acc[ci][j]);
        }
    }

#pragma unroll
    for (int ci = 0; ci < 4; ++ci)
        st4(out + (size_t)(b * C_ + g * GC_ + cg4 * 4 + ci) * HW_ + (r0 + r) * W_ + cq * 4,
            acc[ci]);
}

// ---------------------------------------------------------------------------
extern "C" void kernel_launch(void* const* d_in, const int* in_sizes, int n_in,
                              void* d_out, int out_size, void* d_ws, size_t ws_size,
                              hipStream_t stream) {
    const float* x  = (const float*)d_in[0];
    const float* w1 = (const float*)d_in[1];
    const float* b1 = (const float*)d_in[2];
    const float* w2 = (const float*)d_in[3];
    const float* b2 = (const float*)d_in[4];
    float* out = (float*)d_out;

    // ws: xt bf16 (6.42 MB) | t bf16 (1.6 MB) | wgt bf16 (19.7 MB)
    char* ws = (char*)d_ws;
    __bf16* xt  = (__bf16*)ws;
    __bf16* t   = (__bf16*)(ws + (size_t)NP_ * C_ * 2);
    __bf16* wgt = (__bf16*)(ws + (size_t)NP_ * C_ * 2 + (size_t)NP_ * RED_ * 2);

    xt_kernel <<<dim3(NP_ / 64, C_ / 64), 256, 0, stream>>>(x, xt);
    gen1m     <<<dim3(NP_ / 256),         256, 0, stream>>>(xt, w1, b1, t);
    gen2_mfma <<<dim3(NP_ / 256, 13),     256, 0, stream>>>(t, w2, b2, wgt);
    inv_kernel<<<dim3(14, G_, B_),        256, 0, stream>>>(x, (const u16*)wgt, out);
}

// Round 8
// 121.527 us; speedup vs baseline: 1.2926x; 1.1012x over previous
//
#include <hip/hip_runtime.h>

#define B_    4
#define C_    256
#define Kk    7
#define GC_   16
#define G_    16
#define RED_  64
#define H_    56
#define W_    56
#define HW_   3136
#define KK_   49
#define KG_   784
#define NP_   12544

typedef float  f4    __attribute__((ext_vector_type(4)));
typedef float  f32x4 __attribute__((ext_vector_type(4)));
typedef __bf16 bf16x8 __attribute__((ext_vector_type(8)));
typedef __bf16 bf16x4 __attribute__((ext_vector_type(4)));
typedef unsigned short u16;
typedef u16    u16x4 __attribute__((ext_vector_type(4)));

__device__ __forceinline__ f4 ld4(const float* p) { return *(const f4*)p; }
__device__ __forceinline__ void st4(float* p, f4 v) { *(f4*)p = v; }
__device__ __forceinline__ float bf2f(u16 u) {
    return __uint_as_float(((unsigned)u) << 16);
}

// ---------------------------------------------------------------------------
// xt: transpose x f32 [b][c][p] -> xt bf16 [P][256] (c contiguous).  (r5, verified)
__global__ __launch_bounds__(256) void xt_kernel(const float* __restrict__ x,
                                                 __bf16* __restrict__ xt) {
    __shared__ __bf16 lt[64][68];
    const int tid = threadIdx.x;
    const int P0  = blockIdx.x * 64;
    const int c0  = blockIdx.y * 64;
    const int b   = P0 / HW_;
    const int p0  = P0 - b * HW_;

    const int pq  = tid & 15;
    const int crb = tid >> 4;
#pragma unroll
    for (int i = 0; i < 4; ++i) {
        const int cr = crb + i * 16;
        const f4 v = ld4(x + (size_t)(b * C_ + c0 + cr) * HW_ + p0 + pq * 4);
#pragma unroll
        for (int j = 0; j < 4; ++j) lt[pq * 4 + j][cr] = (__bf16)v[j];
    }
    __syncthreads();
    const int cq  = tid & 15;
    const int plb = tid >> 4;
#pragma unroll
    for (int i = 0; i < 4; ++i) {
        const int pl = plb + i * 16;
        const bf16x4 rv = *(const bf16x4*)&lt[pl][cq * 4];
        *(bf16x4*)(xt + (size_t)(P0 + pl) * C_ + c0 + cq * 4) = rv;
    }
}

// ---------------------------------------------------------------------------
// gen1m2 (MFMA): t[P][64] bf16 = relu(w1 @ x + b1).
// grid (196), block 256 = 4 waves; wave = 16-px N-tile; A = w1 via LDS bf16.
// w1s row stride 260 u16 = 130 dwords == 2 (mod 32): 16 A-rows -> 16 banks.
__global__ __launch_bounds__(256) void gen1m2(const __bf16* __restrict__ xt,
                                              const float* __restrict__ w1,
                                              const float* __restrict__ b1,
                                              __bf16* __restrict__ t) {
    __shared__ __bf16 w1s[64][260];        // 64 rows x 256 c (+4 pad) = 33.3 KB
    const int tid  = threadIdx.x;
    const int lane = tid & 63;
    const int wave = tid >> 6;
    const int row  = lane & 15;
    const int kg   = lane >> 4;
    const int P0w  = blockIdx.x * 64 + wave * 16;

    // hoist all B fragments (8 ksteps) — in flight during LDS fill + barrier
    const __bf16* bp = xt + (size_t)(P0w + row) * C_ + kg * 8;
    bf16x8 bv[8];
#pragma unroll
    for (int ks = 0; ks < 8; ++ks) bv[ks] = *(const bf16x8*)(bp + ks * 32);

    // stage w1 -> LDS bf16 (64 rows x 256 c), 4096 f4-quads
#pragma unroll
    for (int i = 0; i < 16; ++i) {
        const int q  = tid + i * 256;
        const int r  = q >> 6;
        const int c0 = (q & 63) * 4;
        const f4 v = ld4(w1 + (size_t)r * C_ + c0);
        bf16x4 pk;
#pragma unroll
        for (int j = 0; j < 4; ++j) pk[j] = (__bf16)v[j];
        *(bf16x4*)&w1s[r][c0] = pk;
    }
    __syncthreads();

    f32x4 acc[4] = {f32x4(0.f), f32x4(0.f), f32x4(0.f), f32x4(0.f)};
#pragma unroll
    for (int ks = 0; ks < 8; ++ks)
#pragma unroll
        for (int mt = 0; mt < 4; ++mt) {
            const bf16x8 af = *(const bf16x8*)&w1s[mt * 16 + row][ks * 32 + kg * 8];
            acc[mt] = __builtin_amdgcn_mfma_f32_16x16x32_bf16(af, bv[ks], acc[mt], 0, 0, 0);
        }

#pragma unroll
    for (int mt = 0; mt < 4; ++mt) {
        const f4 bias = ld4(b1 + mt * 16 + kg * 4);
        bf16x4 pk;
#pragma unroll
        for (int j = 0; j < 4; ++j)
            pk[j] = (__bf16)fmaxf(acc[mt][j] + bias[j], 0.f);
        *(bf16x4*)(t + (size_t)(P0w + row) * RED_ + mt * 16 + kg * 4) = pk;
    }
}

// ---------------------------------------------------------------------------
// gen2_mfma2: wgt[b][784][3136] bf16 = w2 @ t + b2.
// grid (49, 13), block 256 = 4 waves x 64 px. A = w2 via LDS bf16; B hoisted.
__global__ __launch_bounds__(256) void gen2_mfma2(const __bf16* __restrict__ t,
                                                  const float* __restrict__ w2,
                                                  const float* __restrict__ b2,
                                                  __bf16* __restrict__ wgt) {
    __shared__ __bf16 w2s[64][68];
    const int tid  = threadIdx.x;
    const int lane = tid & 63;
    const int wave = tid >> 6;
    const int row  = lane & 15;
    const int kg   = lane >> 4;
    const int P0   = blockIdx.x * 256 + wave * 64;
    const int k0   = blockIdx.y * 64;
    const int nMt  = (blockIdx.y == 12) ? 1 : 4;       // 784 = 12*64 + 16

    // hoist all B fragments (4 col-groups x 2 ksteps)
    bf16x8 bfrag[4][2];
#pragma unroll
    for (int cg = 0; cg < 4; ++cg)
#pragma unroll
        for (int ks = 0; ks < 2; ++ks)
            bfrag[cg][ks] = *(const bf16x8*)(t + (size_t)(P0 + cg * 16 + row) * RED_
                                               + ks * 32 + kg * 8);

    // stage w2 block rows -> LDS bf16 [64][68]; rows >= 784 zeroed
#pragma unroll
    for (int i = 0; i < 4; ++i) {
        const int q  = tid + i * 256;                  // 1024 f4-quads
        const int r  = q >> 4;
        const int c0 = (q & 15) * 4;
        f4 v = {0.f, 0.f, 0.f, 0.f};
        if (k0 + r < KG_) v = ld4(w2 + (size_t)(k0 + r) * RED_ + c0);
        bf16x4 pk;
#pragma unroll
        for (int j = 0; j < 4; ++j) pk[j] = (__bf16)v[j];
        *(bf16x4*)&w2s[r][c0] = pk;
    }
    __syncthreads();

    for (int mt = 0; mt < nMt; ++mt) {
        const bf16x8 afr0 = *(const bf16x8*)&w2s[mt * 16 + row][kg * 8];
        const bf16x8 afr1 = *(const bf16x8*)&w2s[mt * 16 + row][32 + kg * 8];
        f32x4 acc[4] = {f32x4(0.f), f32x4(0.f), f32x4(0.f), f32x4(0.f)};
#pragma unroll
        for (int cg = 0; cg < 4; ++cg) {
            acc[cg] = __builtin_amdgcn_mfma_f32_16x16x32_bf16(afr0, bfrag[cg][0], acc[cg], 0, 0, 0);
            acc[cg] = __builtin_amdgcn_mfma_f32_16x16x32_bf16(afr1, bfrag[cg][1], acc[cg], 0, 0, 0);
        }
        const f4 bias = ld4(b2 + k0 + mt * 16 + kg * 4);
#pragma unroll
        for (int cg = 0; cg < 4; ++cg) {
            const int Pcg = P0 + cg * 16;
            const int b   = Pcg / HW_;
            const int p   = Pcg - b * HW_ + row;
            const size_t base = ((size_t)b * KG_ + (size_t)(k0 + mt * 16 + kg * 4)) * HW_ + p;
#pragma unroll
            for (int j = 0; j < 4; ++j)
                wgt[base + (size_t)j * HW_] = (__bf16)(acc[cg][j] + bias[j]);
        }
    }
}

// ---------------------------------------------------------------------------
// inv (LDS-staged): unchanged from r5.
#define BR_  4
#define XR_  10
#define XST_ 68
__global__ __launch_bounds__(256) void inv_kernel(const float* __restrict__ x,
                                                  const u16* __restrict__ wgt,
                                                  float* __restrict__ out) {
    __shared__ float xs[GC_][XR_][XST_];
    __shared__ u16   wsm[KK_][BR_][W_];
    const int tid = threadIdx.x;
    const int r0  = blockIdx.x * BR_;
    const int g   = blockIdx.y;
    const int b   = blockIdx.z;

    for (int idx = tid; idx < GC_ * XR_ * 16; idx += 256) {
        const int c   = idx / (XR_ * 16);
        const int rem = idx - c * (XR_ * 16);
        const int hr  = rem >> 4;
        const int wq  = rem & 15;
        const int h   = r0 - 3 + hr;
        f4 v = {0.f, 0.f, 0.f, 0.f};
        if (h >= 0 && h < H_) {
            const float* xr_ = x + (size_t)(b * C_ + g * GC_ + c) * HW_ + h * W_;
            const int w0 = wq * 4 - 3;
            if (wq >= 1 && wq <= 13) {
                v = ld4(xr_ + w0);
            } else {
#pragma unroll
                for (int j = 0; j < 4; ++j) {
                    const int w = w0 + j;
                    if (w >= 0 && w < W_) v[j] = xr_[w];
                }
            }
        }
        *(f4*)&xs[c][hr][wq * 4] = v;
    }
    for (int idx = tid; idx < KK_ * BR_ * 14; idx += 256) {
        const int k   = idx / (BR_ * 14);
        const int rem = idx - k * (BR_ * 14);
        const int r   = rem / 14;
        const int cq  = rem - r * 14;
        const u16x4 v = *(const u16x4*)(wgt + ((size_t)b * KG_ + (size_t)g * KK_ + k) * HW_
                                            + (r0 + r) * W_ + cq * 4);
        *(u16x4*)&wsm[k][r][cq * 4] = v;
    }
    __syncthreads();

    if (tid >= 224) return;
    const int cq  = tid % 14;
    const int r   = (tid / 14) & 3;
    const int cg4 = tid / 56;

    f4 acc[4] = {f4(0.f), f4(0.f), f4(0.f), f4(0.f)};
#pragma unroll
    for (int kh = 0; kh < Kk; ++kh) {
        float tf[7][4];
#pragma unroll
        for (int kw = 0; kw < 7; ++kw) {
            const u16x4 tv = *(const u16x4*)&wsm[kh * 7 + kw][r][cq * 4];
#pragma unroll
            for (int j = 0; j < 4; ++j) tf[kw][j] = bf2f(tv[j]);
        }
        const int hr = r + kh;
#pragma unroll
        for (int ci = 0; ci < 4; ++ci) {
            const float* xrow = &xs[cg4 * 4 + ci][hr][cq * 4];
            const f4 x0 = ld4(xrow), x1 = ld4(xrow + 4), x2 = ld4(xrow + 8);
            float xw[12];
#pragma unroll
            for (int j = 0; j < 4; ++j) { xw[j] = x0[j]; xw[4 + j] = x1[j]; xw[8 + j] = x2[j]; }
#pragma unroll
            for (int kw = 0; kw < 7; ++kw)
#pragma unroll
                for (int j = 0; j < 4; ++j)
                    acc[ci][j] = fmaf(tf[kw][j], xw[j + kw], acc[ci][j]);
        }
    }

#pragma unroll
    for (int ci = 0; ci < 4; ++ci)
        st4(out + (size_t)(b * C_ + g * GC_ + cg4 * 4 + ci) * HW_ + (r0 + r) * W_ + cq * 4,
            acc[ci]);
}

// ---------------------------------------------------------------------------
extern "C" void kernel_launch(void* const* d_in, const int* in_sizes, int n_in,
                              void* d_out, int out_size, void* d_ws, size_t ws_size,
                              hipStream_t stream) {
    const float* x  = (const float*)d_in[0];
    const float* w1 = (const float*)d_in[1];
    const float* b1 = (const float*)d_in[2];
    const float* w2 = (const float*)d_in[3];
    const float* b2 = (const float*)d_in[4];
    float* out = (float*)d_out;

    // ws: xt bf16 (6.42 MB) | t bf16 (1.6 MB) | wgt bf16 (19.7 MB)
    char* ws = (char*)d_ws;
    __bf16* xt  = (__bf16*)ws;
    __bf16* t   = (__bf16*)(ws + (size_t)NP_ * C_ * 2);
    __bf16* wgt = (__bf16*)(ws + (size_t)NP_ * C_ * 2 + (size_t)NP_ * RED_ * 2);

    xt_kernel  <<<dim3(NP_ / 64, C_ / 64), 256, 0, stream>>>(x, xt);
    gen1m2     <<<dim3(NP_ / 64),          256, 0, stream>>>(xt, w1, b1, t);
    gen2_mfma2 <<<dim3(NP_ / 256, 13),     256, 0, stream>>>(t, w2, b2, wgt);
    inv_kernel <<<dim3(14, G_, B_),        256, 0, stream>>>(x, (const u16*)wgt, out);
}